// Round 5
// baseline (270.205 us; speedup 1.0000x reference)
//
#include <hip/hip_runtime.h>

typedef unsigned int u32;
typedef unsigned short u16;

typedef __attribute__((ext_vector_type(8))) short short8v;   // 8 x bf16 bits
typedef __attribute__((ext_vector_type(4))) float f32x4;

#define AS_GLOBAL __attribute__((address_space(1)))
#define AS_LDS    __attribute__((address_space(3)))

static __device__ __forceinline__ u16 f32_bf16_rne(float f) {
  u32 u = __builtin_bit_cast(u32, f);
  u32 lsb = (u >> 16) & 1u;
  u += 0x7fffu + lsb;
  return (u16)(u >> 16);
}

// ---------------------------------------------------------------------------
// Pass 1: quotient-remainder fake quant, f32 -> bf16 bits.
// One group (GS=128) per 16-lane subgroup; 8 elems/lane.
// base >= 2 always, so reference's sel_mask (base < 1.0) is always false.
// ---------------------------------------------------------------------------
__global__ __launch_bounds__(256) void quant_kernel(
    const float* __restrict__ x, u16* __restrict__ xq) {
  const int tid = blockIdx.x * 256 + threadIdx.x;
  const int grp = tid >> 4;
  const int l   = tid & 15;
  const size_t base_e = (size_t)grp * 128;
  const float* gx = x + base_e;

  float4 v0 = *(const float4*)(gx + l * 4);
  float4 v1 = *(const float4*)(gx + 64 + l * 4);
  float xs[8] = {v0.x, v0.y, v0.z, v0.w, v1.x, v1.y, v1.z, v1.w};

  float mabs = 0.f;
  #pragma unroll
  for (int i = 0; i < 8; ++i) mabs = fmaxf(mabs, fabsf(xs[i]));
  #pragma unroll
  for (int s = 1; s < 16; s <<= 1) mabs = fmaxf(mabs, __shfl_xor(mabs, s, 16));
  mabs = fmaxf(mabs, 1e-8f);

  const float thr = mabs / 7.0f;            // true division: matches np
  float base = 64.f;
  base = (thr <= 32.f) ? 32.f : base;
  base = (thr <= 16.f) ? 16.f : base;
  base = (thr <= 8.f)  ? 8.f  : base;
  base = (thr <= 4.f)  ? 4.f  : base;
  base = (thr <= 2.f)  ? 2.f  : base;
  const float rbase = 1.0f / base;          // exact (power of 2)

  float q[8], r[8];
  float mr = 0.f;
  #pragma unroll
  for (int i = 0; i < 8; ++i) {
    float qq = rintf(xs[i] * rbase);        // == rintf(xs/base), exact scale
    qq = fminf(fmaxf(qq, -7.f), 7.f);
    q[i] = qq;
    r[i] = xs[i] - base * qq;               // exact product, IEEE sub
    mr = fmaxf(mr, fabsf(r[i]));
  }
  #pragma unroll
  for (int s = 1; s < 16; s <<= 1) mr = fmaxf(mr, __shfl_xor(mr, s, 16));
  float rs = fmaxf(mr, 1e-8f) / 7.0f;
  rs = fmaxf(rs, 1e-8f);

  u16 o[8];
  #pragma unroll
  for (int i = 0; i < 8; ++i) {
    float rd = rintf(r[i] / rs);            // IEEE division: matches np
    rd = fminf(fmaxf(rd, -8.f), 7.f) * rs;
    o[i] = f32_bf16_rne(q[i] * base + rd);
  }
  uint2 p0, p1;
  p0.x = (u32)o[0] | ((u32)o[1] << 16);
  p0.y = (u32)o[2] | ((u32)o[3] << 16);
  p1.x = (u32)o[4] | ((u32)o[5] << 16);
  p1.y = (u32)o[6] | ((u32)o[7] << 16);
  *(uint2*)(xq + base_e + l * 4) = p0;
  *(uint2*)(xq + base_e + 64 + l * 4) = p1;
}

// ---------------------------------------------------------------------------
// Pass 2: weight f32 -> bf16 bits.
// ---------------------------------------------------------------------------
__global__ __launch_bounds__(256) void wconv_kernel(
    const float* __restrict__ w, u16* __restrict__ wq) {
  const int i = (blockIdx.x * 256 + threadIdx.x) * 4;
  float4 v = *(const float4*)(w + i);
  uint2 p;
  p.x = (u32)f32_bf16_rne(v.x) | ((u32)f32_bf16_rne(v.y) << 16);
  p.y = (u32)f32_bf16_rne(v.z) | ((u32)f32_bf16_rne(v.w) << 16);
  *(uint2*)(wq + i) = p;
}

// ---------------------------------------------------------------------------
// Pass 3: bf16 MFMA GEMM, PERSISTENT: grid=256 (1 block/CU), each block does
// 4 output tiles (fixed nt, 4 mts within its XCD's mt range) as ONE
// continuous 64-step K-stream. 256x256 tile, BK=64, 8 waves (2Mx4N),
// 4 phases/K-step, K-half staging, counted vmcnt(6) across tile boundaries.
//
// ROUND-5 FIX: barriers are __builtin_amdgcn_s_barrier() and waitcnts are
// clobber-FREE asm. The previous asm("s_barrier":::"memory") form made every
// barrier a may-access-memory op -> conservative vmcnt(0)/lgkmcnt(0) drain
// at all 8 barriers/K-step -> pipeline behaved as drain-0 (m218 V1). Plain
// C++ LDS reads get compiler-emitted counted lgkmcnt before MFMA use.
//
// LDS map (128 KiB): A[p] at p*32768, B[p] at 65536+p*32768; within buffer:
// ksub*16384 + row*64 + (kslot ^ ((row>>1)&3))*16. DMA dest linear; source
// pre-swizzled; ds_read applies same XOR -> bank-balanced b128 (conflict=0).
//
// Stage stream (3 half-tiles ahead, vmcnt(6) at ph3):
//   ph0: B[t+1] k1   ph1: A[t+2] k0   ph2: B[t+2] k0   ph3: A[t+2] k1
// At ph3(t) the 6 newest VMEM instrs are the t+2 halves -> vmcnt(6) drains
// exactly through B[t+1]k1, so ALL of tile t+1 is visible after ph3's
// barrier. stage -> vmcnt -> barrier order is side-effect-preserved.
// ---------------------------------------------------------------------------
#define BM 256
#define BN 256
#define BK 64

__global__ __launch_bounds__(512, 2) void gemm_kernel(
    const u16* __restrict__ A, const u16* __restrict__ B,
    const float* __restrict__ bias, float* __restrict__ out,
    int M, int N, int K) {
  __shared__ u16 lds[65536];   // 128 KiB

  const int tid  = threadIdx.x;
  const int w    = tid >> 6;
  const int lane = tid & 63;
  const int l16  = lane & 15;
  const int quad = lane >> 4;

  // persistent-block tile assignment: 32 blocks/XCD, nt fixed per block,
  // mt = xcd*32 + (idx>>2) + 8*seg  (seg = t>>4) -> A panels stay XCD-local
  const int xcd = blockIdx.x & 7;
  const int idx = blockIdx.x >> 3;            // 0..31
  const int n0  = (idx & 3) * BN;
  const int mtl = idx >> 2;                   // 0..7
  const int mtb = xcd * 32 + mtl;
  const int wm = (w >> 2) * 128, wn = (w & 3) * 64;

  const int swz  = (quad ^ ((l16 >> 1) & 3)) << 4;
  const int aoff = (wm + l16) * 64 + swz;
  const int boff = (wn + l16) * 64 + swz;

  // m0 for logical K-step u
  auto m0_of = [&](int u) { return (mtb + 8 * (u >> 4)) * BM; };

  // stage one K-half (16 KB): 2 x global_load_lds dwordx4 per thread
  auto stage_half = [&](const u16* __restrict__ G, int base_b, int r0, int k0) {
    #pragma unroll
    for (int i = 0; i < 2; ++i) {
      const int c = w * 2 + i;                       // 0..15 chunks of 1 KiB
      const int row = c * 16 + (lane >> 2);
      const int kslot = (lane & 3) ^ ((lane >> 3) & 3);   // pre-swizzled src
      const u16* g = G + (size_t)(r0 + row) * K + (k0 + kslot * 8);
      __builtin_amdgcn_global_load_lds((const AS_GLOBAL u32*)(const void*)g,
          (AS_LDS u32*)(void*)((char*)lds + base_b + c * 1024), 16, 0, 0);
    }
  };

  auto LDA = [&](int base_b, int s, int f) {
    return *(const short8v*)((const char*)lds + base_b + s * 16384 + f * 1024 + aoff);
  };
  auto LDB = [&](int base_b, int s, int g) {
    return *(const short8v*)((const char*)lds + base_b + s * 16384 + g * 1024 + boff);
  };

  f32x4 acc[8][4];
  #pragma unroll
  for (int f = 0; f < 8; ++f)
    #pragma unroll
    for (int g = 0; g < 4; ++g)
      acc[f][g] = (f32x4){0.f, 0.f, 0.f, 0.f};

  short8v aA[8], aB[8], b0[2], b1[2];

  const int NTOT = (K / BK) * 4;   // 64 continuous K-steps (4 segments of 16)

  // prologue (once per block): tile0's 4 halves + tile1's first 3, in order
  stage_half(A, 0,             m0_of(0), 0);
  stage_half(B, 65536,         n0, 0);
  stage_half(A, 16384,         m0_of(0), 32);
  stage_half(B, 65536 + 16384, n0, 32);
  stage_half(A, 32768,         m0_of(1), 64);
  stage_half(B, 65536 + 32768, n0, 64);
  stage_half(A, 32768 + 16384, m0_of(1), 96);
  asm volatile("s_waitcnt vmcnt(6)");   // tile0's 8 loads done (no clobber!)
  __builtin_amdgcn_s_barrier();

  // pre-issue reads for t=0 phase 0 (parity 0)
  #pragma unroll
  for (int f = 0; f < 8; ++f) aA[f] = LDA(0, 0, f);
  b0[0] = LDB(65536, 0, 0);
  b0[1] = LDB(65536, 0, 1);

  for (int t = 0; t < NTOT; ++t) {
    const int p   = t & 1;
    const int pAb = p * 32768;
    const int pBb = 65536 + p * 32768;
    const int qAb = (p ^ 1) * 32768;
    const int qBb = 65536 + (p ^ 1) * 32768;
    const int k1s = ((t + 1) & 15) * 64;    // k0 of step t+1
    const int k2s = ((t + 2) & 15) * 64;    // k0 of step t+2

    // -------- phase 0: MFMA (k0, fn 0-1); read b(k0,fn23); stage B[t+1]k1
    b1[0] = LDB(pBb, 0, 2);
    b1[1] = LDB(pBb, 0, 3);
    if (t + 1 < NTOT) stage_half(B, qBb + 16384, n0, k1s + 32);
    __builtin_amdgcn_s_barrier();
    __builtin_amdgcn_s_setprio(1);
    #pragma unroll
    for (int f = 0; f < 8; ++f) {
      acc[f][0] = __builtin_amdgcn_mfma_f32_16x16x32_bf16(aA[f], b0[0], acc[f][0], 0, 0, 0);
      acc[f][1] = __builtin_amdgcn_mfma_f32_16x16x32_bf16(aA[f], b0[1], acc[f][1], 0, 0, 0);
    }
    __builtin_amdgcn_s_setprio(0);
    __builtin_amdgcn_sched_barrier(0);
    __builtin_amdgcn_s_barrier();

    // -------- phase 1: MFMA (k0, fn 2-3); read a(k1)+b(k1,fn01); stage A[t+2]k0
    #pragma unroll
    for (int f = 0; f < 8; ++f) aB[f] = LDA(pAb, 1, f);
    b0[0] = LDB(pBb, 1, 0);
    b0[1] = LDB(pBb, 1, 1);
    if (t + 2 < NTOT) stage_half(A, pAb, m0_of(t + 2), k2s);
    __builtin_amdgcn_s_barrier();
    __builtin_amdgcn_s_setprio(1);
    #pragma unroll
    for (int f = 0; f < 8; ++f) {
      acc[f][2] = __builtin_amdgcn_mfma_f32_16x16x32_bf16(aA[f], b1[0], acc[f][2], 0, 0, 0);
      acc[f][3] = __builtin_amdgcn_mfma_f32_16x16x32_bf16(aA[f], b1[1], acc[f][3], 0, 0, 0);
    }
    __builtin_amdgcn_s_setprio(0);
    __builtin_amdgcn_sched_barrier(0);
    __builtin_amdgcn_s_barrier();

    // -------- phase 2: MFMA (k1, fn 0-1); read b(k1,fn23); stage B[t+2]k0
    b1[0] = LDB(pBb, 1, 2);
    b1[1] = LDB(pBb, 1, 3);
    if (t + 2 < NTOT) stage_half(B, pBb, n0, k2s);
    __builtin_amdgcn_s_barrier();
    __builtin_amdgcn_s_setprio(1);
    #pragma unroll
    for (int f = 0; f < 8; ++f) {
      acc[f][0] = __builtin_amdgcn_mfma_f32_16x16x32_bf16(aB[f], b0[0], acc[f][0], 0, 0, 0);
      acc[f][1] = __builtin_amdgcn_mfma_f32_16x16x32_bf16(aB[f], b0[1], acc[f][1], 0, 0, 0);
    }
    __builtin_amdgcn_s_setprio(0);
    __builtin_amdgcn_sched_barrier(0);
    __builtin_amdgcn_s_barrier();

    // -------- phase 3: MFMA (k1, fn 2-3); stage A[t+2]k1; vmcnt(6);
    //          then (after barrier) read step t+1's a(k0)+b(k0,fn01)
    if (t + 2 < NTOT) stage_half(A, pAb + 16384, m0_of(t + 2), k2s + 32);
    if (t < NTOT - 2)       asm volatile("s_waitcnt vmcnt(6)");
    else if (t == NTOT - 2) asm volatile("s_waitcnt vmcnt(0)");
    __builtin_amdgcn_s_barrier();
    if (t + 1 < NTOT) {
      #pragma unroll
      for (int f = 0; f < 8; ++f) aA[f] = LDA(qAb, 0, f);
      b0[0] = LDB(qBb, 0, 0);
      b0[1] = LDB(qBb, 0, 1);
    }
    __builtin_amdgcn_s_setprio(1);
    #pragma unroll
    for (int f = 0; f < 8; ++f) {
      acc[f][2] = __builtin_amdgcn_mfma_f32_16x16x32_bf16(aB[f], b1[0], acc[f][2], 0, 0, 0);
      acc[f][3] = __builtin_amdgcn_mfma_f32_16x16x32_bf16(aB[f], b1[1], acc[f][3], 0, 0, 0);
    }
    __builtin_amdgcn_s_setprio(0);
    __builtin_amdgcn_sched_barrier(0);
    __builtin_amdgcn_s_barrier();

    // -------- segment epilogue: flush acc, zero, keep streaming
    if ((t & 15) == 15) {
      const int m0 = m0_of(t);
      #pragma unroll
      for (int g = 0; g < 4; ++g) {
        const int col = n0 + wn + g * 16 + l16;
        const float bv = bias[col];
        #pragma unroll
        for (int f = 0; f < 8; ++f) {
          const int r0 = m0 + wm + f * 16 + quad * 4;
          #pragma unroll
          for (int j = 0; j < 4; ++j)
            out[(size_t)(r0 + j) * N + col] = acc[f][g][j] + bv;
        }
      }
      #pragma unroll
      for (int f = 0; f < 8; ++f)
        #pragma unroll
        for (int g = 0; g < 4; ++g)
          acc[f][g] = (f32x4){0.f, 0.f, 0.f, 0.f};
    }
  }
}

// ---------------------------------------------------------------------------
extern "C" void kernel_launch(void* const* d_in, const int* in_sizes, int n_in,
                              void* d_out, int out_size, void* d_ws, size_t ws_size,
                              hipStream_t stream) {
  const float* x    = (const float*)d_in[0];   // [8,8192,1024] f32
  const float* wgt  = (const float*)d_in[1];   // [1024,1024] f32
  const float* bias = (const float*)d_in[2];   // [1024] f32
  float* out = (float*)d_out;                  // [8,8192,1024] f32

  const int K = 1024, N = 1024;
  const int M = in_sizes[0] / K;               // 65536

  u16* xq = (u16*)d_ws;                        // 128 MiB bf16
  u16* wq = xq + (size_t)M * K;                // 2 MiB bf16

  const int ngroups = (M * K) / 128;
  quant_kernel<<<ngroups / 16, 256, 0, stream>>>(x, xq);
  wconv_kernel<<<(N * K) / 1024, 256, 0, stream>>>(wgt, wq);
  gemm_kernel<<<256, 512, 0, stream>>>(xq, wq, bias, out, M, N, K);
}